// Round 1
// baseline (991.844 us; speedup 1.0000x reference)
//
#include <hip/hip_runtime.h>
#include <math.h>

#define RK   16
#define H0   512
#define W0   1024
#define H1   2048
#define W1   4096
#define HW0  (H0*W0)
#define HW1  (H1*W1)
#define NH   128
#define BLK  256

// spatial sort tiling: 32x32-pixel tiles on map1 (2048x4096) -> 64x128 = 8192 tiles
#define TSH   5
#define TNX   (W1 >> TSH)       // 128
#define TNY   (H1 >> TSH)       // 64
#define NTILE (TNX * TNY)       // 8192

typedef float f32x4 __attribute__((ext_vector_type(4)));

__device__ __forceinline__ float softplusf(float x) {
    return fmaxf(x, 0.f) + log1pf(expf(-fabsf(x)));
}

__device__ __forceinline__ unsigned bf16rne(float f) {
    unsigned x = __float_as_uint(f);
    return (x + 0x7fffu + ((x >> 16) & 1u)) >> 16;
}

// ---- shared inline pieces ------------------------------------------------

__device__ __forceinline__ void stage_weights(
    const float* __restrict__ w1, const float* __restrict__ w2,
    float* w1T, float* w2s)
{
    const int t = threadIdx.x;
    for (int i = t; i < NH * 16; i += BLK) {
        int j = i >> 4, r = i & 15;
        w1T[i] = w1[r * NH + j];
    }
    for (int i = t; i < NH * 4; i += BLK) {
        int j = i >> 2, c = i & 3;
        w2s[i] = (c < 3) ? w2[j * 3 + c] : 0.f;
    }
}

__device__ __forceinline__ void compute_angles(
    float x, float y, float z, float* gx, float* gy)
{
    float inv = 1.f / (sqrtf(fmaf(x, x, fmaf(y, y, z * z))) + 1e-8f);
    float dx = x * inv, dy = y * inv, dz = z * inv;
    const float INVPI = 0.31830988618379067154f;
    *gx = atan2f(dx, dy) * INVPI;
    float cz = fminf(fmaxf(dz, -1.f), 1.f);
    *gy = acosf(cz) * (2.f * INVPI) - 1.f;
}

__device__ __forceinline__ void make_offsets(
    float gx, float gy, int* off, float* wt)
{
    {
        float px = (gx + 1.f) * (0.5f * W0) - 0.5f;
        float py = (gy + 1.f) * (0.5f * H0) - 0.5f;
        float fx0 = floorf(px), fy0 = floorf(py);
        int x0 = (int)fx0, y0 = (int)fy0, x1 = x0 + 1, y1 = y0 + 1;
        float wx1 = px - fx0, wy1 = py - fy0;
        float wx0 = 1.f - wx1, wy0 = 1.f - wy1;
        bool vx0 = (x0 >= 0) & (x0 < W0), vx1 = (x1 >= 0) & (x1 < W0);
        bool vy0 = (y0 >= 0) & (y0 < H0), vy1 = (y1 >= 0) & (y1 < H0);
        int xc0 = min(max(x0, 0), W0 - 1), xc1 = min(max(x1, 0), W0 - 1);
        int yc0 = min(max(y0, 0), H0 - 1), yc1 = min(max(y1, 0), H0 - 1);
        off[0] = yc0 * W0 + xc0; wt[0] = (vx0 && vy0) ? wx0 * wy0 : 0.f;
        off[1] = yc0 * W0 + xc1; wt[1] = (vx1 && vy0) ? wx1 * wy0 : 0.f;
        off[2] = yc1 * W0 + xc0; wt[2] = (vx0 && vy1) ? wx0 * wy1 : 0.f;
        off[3] = yc1 * W0 + xc1; wt[3] = (vx1 && vy1) ? wx1 * wy1 : 0.f;
    }
    {
        float px = (gx + 1.f) * (0.5f * W1) - 0.5f;
        float py = (gy + 1.f) * (0.5f * H1) - 0.5f;
        float fx0 = floorf(px), fy0 = floorf(py);
        int x0 = (int)fx0, y0 = (int)fy0, x1 = x0 + 1, y1 = y0 + 1;
        float wx1 = px - fx0, wy1 = py - fy0;
        float wx0 = 1.f - wx1, wy0 = 1.f - wy1;
        bool vx0 = (x0 >= 0) & (x0 < W1), vx1 = (x1 >= 0) & (x1 < W1);
        bool vy0 = (y0 >= 0) & (y0 < H1), vy1 = (y1 >= 0) & (y1 < H1);
        int xc0 = min(max(x0, 0), W1 - 1), xc1 = min(max(x1, 0), W1 - 1);
        int yc0 = min(max(y0, 0), H1 - 1), yc1 = min(max(y1, 0), H1 - 1);
        off[4] = yc0 * W1 + xc0; wt[4] = (vx0 && vy0) ? 0.5f * wx0 * wy0 : 0.f;
        off[5] = yc0 * W1 + xc1; wt[5] = (vx1 && vy0) ? 0.5f * wx1 * wy0 : 0.f;
        off[6] = yc1 * W1 + xc0; wt[6] = (vx0 && vy1) ? 0.5f * wx0 * wy1 : 0.f;
        off[7] = yc1 * W1 + xc1; wt[7] = (vx1 && vy1) ? 0.5f * wx1 * wy1 : 0.f;
    }
}

__device__ __forceinline__ void accum_corner(
    const unsigned* __restrict__ mat, int off, float wt, float* emb)
{
    const uint4* q = (const uint4*)(mat + (size_t)off * 8);
    uint4 u0 = q[0];
    uint4 u1 = q[1];
    unsigned w[8] = {u0.x, u0.y, u0.z, u0.w, u1.x, u1.y, u1.z, u1.w};
    #pragma unroll
    for (int r = 0; r < 8; ++r) {
        float lo = __uint_as_float(w[r] << 16);
        float hi = __uint_as_float(w[r] & 0xffff0000u);
        emb[2 * r]     = fmaf(lo, wt, emb[2 * r]);
        emb[2 * r + 1] = fmaf(hi, wt, emb[2 * r + 1]);
    }
}

__device__ __forceinline__ void mlp_store(
    const float* emb, const float* w1T, const float* w2s,
    float* __restrict__ out, int id)
{
    float a0 = 0.f, a1 = 0.f, a2 = 0.f;
    #pragma unroll 8
    for (int j = 0; j < NH; ++j) {
        const float4* wp = (const float4*)&w1T[j * 16];
        float4 c0 = wp[0], c1 = wp[1], c2 = wp[2], c3 = wp[3];
        float h;
        h = emb[0] * c0.x;
        h = fmaf(emb[1],  c0.y, h);
        h = fmaf(emb[2],  c0.z, h);
        h = fmaf(emb[3],  c0.w, h);
        h = fmaf(emb[4],  c1.x, h);
        h = fmaf(emb[5],  c1.y, h);
        h = fmaf(emb[6],  c1.z, h);
        h = fmaf(emb[7],  c1.w, h);
        h = fmaf(emb[8],  c2.x, h);
        h = fmaf(emb[9],  c2.y, h);
        h = fmaf(emb[10], c2.z, h);
        h = fmaf(emb[11], c2.w, h);
        h = fmaf(emb[12], c3.x, h);
        h = fmaf(emb[13], c3.y, h);
        h = fmaf(emb[14], c3.z, h);
        h = fmaf(emb[15], c3.w, h);
        h = fmaxf(h, 0.f);
        a0 = fmaf(h, w2s[j * 4 + 0], a0);
        a1 = fmaf(h, w2s[j * 4 + 1], a1);
        a2 = fmaf(h, w2s[j * 4 + 2], a2);
    }
    out[id * 3 + 0] = softplusf(a0);
    out[id * 3 + 1] = softplusf(a1);
    out[id * 3 + 2] = softplusf(a2);
}

// ---- repack (16,H,W) fp32 -> (H,W,16) bf16, 4 pixels/thread, vectorized ----
// Non-temporal src loads: don't let the 512MB fp32 read stream evict the
// m1p store stream from L3 (the gather wants m1p resident).
__global__ __launch_bounds__(BLK) void repack4_kernel(
    const float* __restrict__ src, unsigned* __restrict__ dst, int HW)
{
    int p0 = (blockIdx.x * BLK + threadIdx.x) * 4;
    if (p0 >= HW) return;
    f32x4 v[16];
    #pragma unroll
    for (int r = 0; r < 16; ++r)
        v[r] = __builtin_nontemporal_load((const f32x4*)(src + (size_t)r * HW + p0));
    unsigned u[4][8];
    #pragma unroll
    for (int r = 0; r < 8; ++r) {
        f32x4 a = v[2 * r], b = v[2 * r + 1];
        u[0][r] = bf16rne(a.x) | (bf16rne(b.x) << 16);
        u[1][r] = bf16rne(a.y) | (bf16rne(b.y) << 16);
        u[2][r] = bf16rne(a.z) | (bf16rne(b.z) << 16);
        u[3][r] = bf16rne(a.w) | (bf16rne(b.w) << 16);
    }
    uint4* q = (uint4*)(dst + (size_t)p0 * 8);
    #pragma unroll
    for (int px = 0; px < 4; ++px) {
        q[px * 2 + 0] = make_uint4(u[px][0], u[px][1], u[px][2], u[px][3]);
        q[px * 2 + 1] = make_uint4(u[px][4], u[px][5], u[px][6], u[px][7]);
    }
}

// ---- sort pass 0: zero the tile histogram ----
__global__ __launch_bounds__(256) void zero_kernel(unsigned* __restrict__ hist)
{
    int i = blockIdx.x * 256 + threadIdx.x;
    if (i < NTILE) hist[i] = 0u;
}

// ---- sort pass 1: angles + tile key + histogram + record ----
__global__ __launch_bounds__(BLK) void angle_kernel(
    const float* __restrict__ vd, uint4* __restrict__ rec,
    unsigned* __restrict__ hist, int B)
{
    int b = blockIdx.x * BLK + threadIdx.x;
    if (b >= B) return;
    float gx, gy;
    compute_angles(vd[b * 3 + 0], vd[b * 3 + 1], vd[b * 3 + 2], &gx, &gy);
    // tile key on map1 coordinates
    float px = (gx + 1.f) * (0.5f * W1) - 0.5f;
    float py = (gy + 1.f) * (0.5f * H1) - 0.5f;
    int xi = min(max((int)floorf(px), 0), W1 - 1) >> TSH;
    int yi = min(max((int)floorf(py), 0), H1 - 1) >> TSH;
    unsigned key = (unsigned)(yi * TNX + xi);
    atomicAdd(&hist[key], 1u);
    rec[b] = make_uint4(__float_as_uint(gx), __float_as_uint(gy), (unsigned)b, key);
}

// ---- sort pass 2: exclusive scan of 8192-bin histogram (one block) ----
__global__ __launch_bounds__(256) void scan_kernel(
    const unsigned* __restrict__ hist, unsigned* __restrict__ offs)
{
    __shared__ unsigned s[256];
    const int t = threadIdx.x;
    unsigned local[32];
    unsigned sum = 0;
    #pragma unroll
    for (int i = 0; i < 32; ++i) { local[i] = hist[t * 32 + i]; sum += local[i]; }
    s[t] = sum;
    __syncthreads();
    for (int o = 1; o < 256; o <<= 1) {
        unsigned v = (t >= o) ? s[t - o] : 0u;
        __syncthreads();
        s[t] += v;
        __syncthreads();
    }
    unsigned run = s[t] - sum;   // exclusive prefix of this thread's chunk
    #pragma unroll
    for (int i = 0; i < 32; ++i) { offs[t * 32 + i] = run; run += local[i]; }
}

// ---- sort pass 3: scatter records into tile order ----
__global__ __launch_bounds__(BLK) void scatter_kernel(
    const uint4* __restrict__ rec, unsigned* __restrict__ offs,
    uint4* __restrict__ srec, int B)
{
    int b = blockIdx.x * BLK + threadIdx.x;
    if (b >= B) return;
    uint4 r = rec[b];
    unsigned pos = atomicAdd(&offs[r.w], 1u);
    srec[pos] = r;
}

// ---- fused gather + MLP over spatially-sorted points ----
__global__ __launch_bounds__(BLK) void bg_gather_sorted_kernel(
    const uint4* __restrict__ srec,
    const unsigned* __restrict__ m0p,
    const unsigned* __restrict__ m1p,
    const float* __restrict__ w1,
    const float* __restrict__ w2,
    float* __restrict__ out,
    int B)
{
    __shared__ float w1T[NH * 16];
    __shared__ float w2s[NH * 4];
    stage_weights(w1, w2, w1T, w2s);
    __syncthreads();

    const int b = blockIdx.x * BLK + threadIdx.x;
    if (b >= B) return;

    uint4 r = srec[b];
    float gx = __uint_as_float(r.x);
    float gy = __uint_as_float(r.y);
    int   id = (int)r.z;

    int   off[8];
    float wt[8];
    make_offsets(gx, gy, off, wt);

    float emb[RK];
    #pragma unroll
    for (int k = 0; k < RK; ++k) emb[k] = 0.f;
    accum_corner(m0p, off[0], wt[0], emb);
    accum_corner(m0p, off[1], wt[1], emb);
    accum_corner(m0p, off[2], wt[2], emb);
    accum_corner(m0p, off[3], wt[3], emb);
    accum_corner(m1p, off[4], wt[4], emb);
    accum_corner(m1p, off[5], wt[5], emb);
    accum_corner(m1p, off[6], wt[6], emb);
    accum_corner(m1p, off[7], wt[7], emb);

    mlp_store(emb, w1T, w2s, out, id);
}

// ---- unsorted gather (previous best, mid-size ws fallback) ----
__global__ __launch_bounds__(BLK) void bg_gather_kernel(
    const float* __restrict__ vd,
    const unsigned* __restrict__ m0p,
    const unsigned* __restrict__ m1p,
    const float* __restrict__ w1,
    const float* __restrict__ w2,
    float* __restrict__ out,
    int B)
{
    __shared__ float w1T[NH * 16];
    __shared__ float w2s[NH * 4];
    stage_weights(w1, w2, w1T, w2s);
    __syncthreads();

    const int b = blockIdx.x * BLK + threadIdx.x;
    if (b >= B) return;

    float gx, gy;
    compute_angles(vd[b * 3 + 0], vd[b * 3 + 1], vd[b * 3 + 2], &gx, &gy);

    int   off[8];
    float wt[8];
    make_offsets(gx, gy, off, wt);

    float emb[RK];
    #pragma unroll
    for (int k = 0; k < RK; ++k) emb[k] = 0.f;
    accum_corner(m0p, off[0], wt[0], emb);
    accum_corner(m0p, off[1], wt[1], emb);
    accum_corner(m0p, off[2], wt[2], emb);
    accum_corner(m0p, off[3], wt[3], emb);
    accum_corner(m1p, off[4], wt[4], emb);
    accum_corner(m1p, off[5], wt[5], emb);
    accum_corner(m1p, off[6], wt[6], emb);
    accum_corner(m1p, off[7], wt[7], emb);

    mlp_store(emb, w1T, w2s, out, b);
}

// ---- tiny-ws fallback: direct fp32 gather from channel-major maps ----
__global__ __launch_bounds__(BLK) void bg_fused_kernel(
    const float* __restrict__ vd,
    const float* __restrict__ m0,
    const float* __restrict__ m1,
    const float* __restrict__ w1,
    const float* __restrict__ w2,
    float* __restrict__ out,
    int B)
{
    __shared__ float w1T[NH * 16];
    __shared__ float w2s[NH * 4];
    stage_weights(w1, w2, w1T, w2s);
    __syncthreads();

    const int b = blockIdx.x * BLK + threadIdx.x;
    if (b >= B) return;

    float gx, gy;
    compute_angles(vd[b * 3 + 0], vd[b * 3 + 1], vd[b * 3 + 2], &gx, &gy);

    int   off[8];
    float wt[8];
    make_offsets(gx, gy, off, wt);

    float emb[RK];
    #pragma unroll
    for (int k = 0; k < RK; ++k) {
        const float* p0 = m0 + k * HW0;
        const float* p1 = m1 + (size_t)k * HW1;
        float v = p0[off[0]] * wt[0];
        v = fmaf(p0[off[1]], wt[1], v);
        v = fmaf(p0[off[2]], wt[2], v);
        v = fmaf(p0[off[3]], wt[3], v);
        v = fmaf(p1[off[4]], wt[4], v);
        v = fmaf(p1[off[5]], wt[5], v);
        v = fmaf(p1[off[6]], wt[6], v);
        v = fmaf(p1[off[7]], wt[7], v);
        emb[k] = v;
    }

    mlp_store(emb, w1T, w2s, out, b);
}

extern "C" void kernel_launch(void* const* d_in, const int* in_sizes, int n_in,
                              void* d_out, int out_size, void* d_ws, size_t ws_size,
                              hipStream_t stream) {
    const float* vd = (const float*)d_in[0];
    const float* m0 = (const float*)d_in[1];
    const float* m1 = (const float*)d_in[2];
    const float* w1 = (const float*)d_in[3];
    const float* w2 = (const float*)d_in[4];
    float* out = (float*)d_out;
    int B = in_sizes[0] / 3;
    int gridB = (B + BLK - 1) / BLK;

    size_t m1p_b  = (size_t)HW1 * 32;
    size_t m0p_b  = (size_t)HW0 * 32;
    size_t rec_b  = (size_t)B * 16;
    size_t hist_b = (size_t)NTILE * 4;
    size_t need_sorted = m1p_b + m0p_b + 2 * rec_b + 2 * hist_b;
    size_t need_basic  = m1p_b + m0p_b;

    if (ws_size >= need_sorted) {
        char* p = (char*)d_ws;
        unsigned* m1p = (unsigned*)p;  p += m1p_b;
        unsigned* m0p = (unsigned*)p;  p += m0p_b;
        uint4*    rec = (uint4*)p;     p += rec_b;
        uint4*    srec = (uint4*)p;    p += rec_b;
        unsigned* hist = (unsigned*)p; p += hist_b;
        unsigned* offs = (unsigned*)p;

        // Sort first (cheap, doesn't disturb L3), then repacks immediately
        // before the gather so m1p is L3-warm when the gather starts.
        zero_kernel<<<(NTILE + 255) / 256, 256, 0, stream>>>(hist);
        angle_kernel<<<gridB, BLK, 0, stream>>>(vd, rec, hist, B);
        scan_kernel<<<1, 256, 0, stream>>>(hist, offs);
        scatter_kernel<<<gridB, BLK, 0, stream>>>(rec, offs, srec, B);
        repack4_kernel<<<HW0 / 4 / BLK, BLK, 0, stream>>>(m0, m0p, HW0);
        repack4_kernel<<<HW1 / 4 / BLK, BLK, 0, stream>>>(m1, m1p, HW1);
        bg_gather_sorted_kernel<<<gridB, BLK, 0, stream>>>(srec, m0p, m1p, w1, w2, out, B);
    } else if (ws_size >= need_basic) {
        unsigned* m1p = (unsigned*)d_ws;
        unsigned* m0p = (unsigned*)d_ws + (size_t)HW1 * 8;
        repack4_kernel<<<HW1 / 4 / BLK, BLK, 0, stream>>>(m1, m1p, HW1);
        repack4_kernel<<<HW0 / 4 / BLK, BLK, 0, stream>>>(m0, m0p, HW0);
        bg_gather_kernel<<<gridB, BLK, 0, stream>>>(vd, m0p, m1p, w1, w2, out, B);
    } else {
        bg_fused_kernel<<<gridB, BLK, 0, stream>>>(vd, m0, m1, w1, w2, out, B);
    }
}

// Round 2
// 845.892 us; speedup vs baseline: 1.1725x; 1.1725x over previous
//
#include <hip/hip_runtime.h>
#include <math.h>

#define RK   16
#define H0   512
#define W0   1024
#define H1   2048
#define W1   4096
#define HW0  (H0*W0)
#define HW1  (H1*W1)
#define NH   128
#define BLK  256

__device__ __forceinline__ float softplusf(float x) {
    return fmaxf(x, 0.f) + log1pf(expf(-fabsf(x)));
}

__device__ __forceinline__ unsigned bf16rne(float f) {
    unsigned x = __float_as_uint(f);
    return (x + 0x7fffu + ((x >> 16) & 1u)) >> 16;
}

// ---- shared inline pieces ------------------------------------------------

__device__ __forceinline__ void compute_angles(
    float x, float y, float z, float* gx, float* gy)
{
    float inv = 1.f / (sqrtf(fmaf(x, x, fmaf(y, y, z * z))) + 1e-8f);
    float dx = x * inv, dy = y * inv, dz = z * inv;
    const float INVPI = 0.31830988618379067154f;
    *gx = atan2f(dx, dy) * INVPI;
    float cz = fminf(fmaxf(dz, -1.f), 1.f);
    *gy = acosf(cz) * (2.f * INVPI) - 1.f;
}

__device__ __forceinline__ void make_offsets(
    float gx, float gy, int* off, float* wt)
{
    {
        float px = (gx + 1.f) * (0.5f * W0) - 0.5f;
        float py = (gy + 1.f) * (0.5f * H0) - 0.5f;
        float fx0 = floorf(px), fy0 = floorf(py);
        int x0 = (int)fx0, y0 = (int)fy0, x1 = x0 + 1, y1 = y0 + 1;
        float wx1 = px - fx0, wy1 = py - fy0;
        float wx0 = 1.f - wx1, wy0 = 1.f - wy1;
        bool vx0 = (x0 >= 0) & (x0 < W0), vx1 = (x1 >= 0) & (x1 < W0);
        bool vy0 = (y0 >= 0) & (y0 < H0), vy1 = (y1 >= 0) & (y1 < H0);
        int xc0 = min(max(x0, 0), W0 - 1), xc1 = min(max(x1, 0), W0 - 1);
        int yc0 = min(max(y0, 0), H0 - 1), yc1 = min(max(y1, 0), H0 - 1);
        off[0] = yc0 * W0 + xc0; wt[0] = (vx0 && vy0) ? wx0 * wy0 : 0.f;
        off[1] = yc0 * W0 + xc1; wt[1] = (vx1 && vy0) ? wx1 * wy0 : 0.f;
        off[2] = yc1 * W0 + xc0; wt[2] = (vx0 && vy1) ? wx0 * wy1 : 0.f;
        off[3] = yc1 * W0 + xc1; wt[3] = (vx1 && vy1) ? wx1 * wy1 : 0.f;
    }
    {
        float px = (gx + 1.f) * (0.5f * W1) - 0.5f;
        float py = (gy + 1.f) * (0.5f * H1) - 0.5f;
        float fx0 = floorf(px), fy0 = floorf(py);
        int x0 = (int)fx0, y0 = (int)fy0, x1 = x0 + 1, y1 = y0 + 1;
        float wx1 = px - fx0, wy1 = py - fy0;
        float wx0 = 1.f - wx1, wy0 = 1.f - wy1;
        bool vx0 = (x0 >= 0) & (x0 < W1), vx1 = (x1 >= 0) & (x1 < W1);
        bool vy0 = (y0 >= 0) & (y0 < H1), vy1 = (y1 >= 0) & (y1 < H1);
        int xc0 = min(max(x0, 0), W1 - 1), xc1 = min(max(x1, 0), W1 - 1);
        int yc0 = min(max(y0, 0), H1 - 1), yc1 = min(max(y1, 0), H1 - 1);
        off[4] = yc0 * W1 + xc0; wt[4] = (vx0 && vy0) ? 0.5f * wx0 * wy0 : 0.f;
        off[5] = yc0 * W1 + xc1; wt[5] = (vx1 && vy0) ? 0.5f * wx1 * wy0 : 0.f;
        off[6] = yc1 * W1 + xc0; wt[6] = (vx0 && vy1) ? 0.5f * wx0 * wy1 : 0.f;
        off[7] = yc1 * W1 + xc1; wt[7] = (vx1 && vy1) ? 0.5f * wx1 * wy1 : 0.f;
    }
}

__device__ __forceinline__ void accum_corner(
    const unsigned* __restrict__ mat, int off, float wt, float* emb)
{
    const uint4* q = (const uint4*)(mat + (size_t)off * 8);
    uint4 u0 = q[0];
    uint4 u1 = q[1];
    unsigned w[8] = {u0.x, u0.y, u0.z, u0.w, u1.x, u1.y, u1.z, u1.w};
    #pragma unroll
    for (int r = 0; r < 8; ++r) {
        float lo = __uint_as_float(w[r] << 16);
        float hi = __uint_as_float(w[r] & 0xffff0000u);
        emb[2 * r]     = fmaf(lo, wt, emb[2 * r]);
        emb[2 * r + 1] = fmaf(hi, wt, emb[2 * r + 1]);
    }
}

// MLP using wave-uniform (scalar-cached) weight reads from prepped global
// buffer: wq = w1T[128][16], w2q = w2pad[128][4]. No LDS anywhere.
__device__ __forceinline__ void mlp_store_scalar(
    const float* emb,
    const float* __restrict__ wq,
    const float* __restrict__ w2q,
    float* __restrict__ out, int id)
{
    float a0 = 0.f, a1 = 0.f, a2 = 0.f;
    #pragma unroll 4
    for (int j = 0; j < NH; ++j) {
        const float4* wp4 = (const float4*)(wq + j * 16);   // uniform -> s_load
        float4 c0 = wp4[0], c1 = wp4[1], c2 = wp4[2], c3 = wp4[3];
        float h;
        h = emb[0] * c0.x;
        h = fmaf(emb[1],  c0.y, h);
        h = fmaf(emb[2],  c0.z, h);
        h = fmaf(emb[3],  c0.w, h);
        h = fmaf(emb[4],  c1.x, h);
        h = fmaf(emb[5],  c1.y, h);
        h = fmaf(emb[6],  c1.z, h);
        h = fmaf(emb[7],  c1.w, h);
        h = fmaf(emb[8],  c2.x, h);
        h = fmaf(emb[9],  c2.y, h);
        h = fmaf(emb[10], c2.z, h);
        h = fmaf(emb[11], c2.w, h);
        h = fmaf(emb[12], c3.x, h);
        h = fmaf(emb[13], c3.y, h);
        h = fmaf(emb[14], c3.z, h);
        h = fmaf(emb[15], c3.w, h);
        h = fmaxf(h, 0.f);
        float4 d = ((const float4*)(w2q + j * 4))[0];        // uniform -> s_load
        a0 = fmaf(h, d.x, a0);
        a1 = fmaf(h, d.y, a1);
        a2 = fmaf(h, d.z, a2);
    }
    out[id * 3 + 0] = softplusf(a0);
    out[id * 3 + 1] = softplusf(a1);
    out[id * 3 + 2] = softplusf(a2);
}

// ---- repack (16, H, W) fp32 -> (H, W, 16) bf16 (R0 kernel, known-good) ----
__global__ __launch_bounds__(BLK) void repack_kernel(
    const float* __restrict__ src, unsigned* __restrict__ dst, int HW)
{
    int p = blockIdx.x * BLK + threadIdx.x;
    if (p >= HW) return;
    unsigned u[8];
    #pragma unroll
    for (int r = 0; r < 8; ++r) {
        float a = src[(2 * r) * HW + p];      // channel 2r   -> low 16
        float b = src[(2 * r + 1) * HW + p];  // channel 2r+1 -> high 16
        u[r] = bf16rne(a) | (bf16rne(b) << 16);
    }
    uint4* q = (uint4*)(dst + (size_t)p * 8);
    q[0] = make_uint4(u[0], u[1], u[2], u[3]);
    q[1] = make_uint4(u[4], u[5], u[6], u[7]);
}

// ---- weight prep: w1 (16,128) -> w1T[128][16]; w2 (128,3) -> [128][4] ----
__global__ __launch_bounds__(BLK) void prep_weights_kernel(
    const float* __restrict__ w1, const float* __restrict__ w2,
    float* __restrict__ wp)
{
    int i = blockIdx.x * BLK + threadIdx.x;
    if (i < NH * 16) {
        int j = i >> 4, r = i & 15;
        wp[i] = w1[r * NH + j];
    }
    if (i < NH * 4) {
        int j = i >> 2, c = i & 3;
        wp[NH * 16 + i] = (c < 3) ? w2[j * 3 + c] : 0.f;
    }
}

// ---- fused gather + MLP, packed bf16 maps + scalar weight loads ----
__global__ __launch_bounds__(BLK) void bg_gather_kernel(
    const float* __restrict__ vd,
    const unsigned* __restrict__ m0p,
    const unsigned* __restrict__ m1p,
    const float* __restrict__ wq,    // prepped w1T [128][16]
    const float* __restrict__ w2q,   // prepped w2  [128][4]
    float* __restrict__ out,
    int B)
{
    const int b = blockIdx.x * BLK + threadIdx.x;
    if (b >= B) return;

    float gx, gy;
    compute_angles(vd[b * 3 + 0], vd[b * 3 + 1], vd[b * 3 + 2], &gx, &gy);

    int   off[8];
    float wt[8];
    make_offsets(gx, gy, off, wt);

    float emb[RK];
    #pragma unroll
    for (int k = 0; k < RK; ++k) emb[k] = 0.f;
    accum_corner(m0p, off[0], wt[0], emb);
    accum_corner(m0p, off[1], wt[1], emb);
    accum_corner(m0p, off[2], wt[2], emb);
    accum_corner(m0p, off[3], wt[3], emb);
    accum_corner(m1p, off[4], wt[4], emb);
    accum_corner(m1p, off[5], wt[5], emb);
    accum_corner(m1p, off[6], wt[6], emb);
    accum_corner(m1p, off[7], wt[7], emb);

    mlp_store_scalar(emb, wq, w2q, out, b);
}

// ---- tiny-ws fallback: direct fp32 gather, LDS weights (R0 kernel) ----
__global__ __launch_bounds__(BLK) void bg_fused_kernel(
    const float* __restrict__ vd,
    const float* __restrict__ m0,
    const float* __restrict__ m1,
    const float* __restrict__ w1,
    const float* __restrict__ w2,
    float* __restrict__ out,
    int B)
{
    __shared__ float w1T[NH * 16];
    __shared__ float w2s[NH * 4];

    const int t = threadIdx.x;
    for (int i = t; i < NH * 16; i += BLK) {
        int j = i >> 4, r = i & 15;
        w1T[i] = w1[r * NH + j];
    }
    for (int i = t; i < NH * 4; i += BLK) {
        int j = i >> 2, c = i & 3;
        w2s[i] = (c < 3) ? w2[j * 3 + c] : 0.f;
    }
    __syncthreads();

    const int b = blockIdx.x * BLK + t;
    if (b >= B) return;

    float gx, gy;
    compute_angles(vd[b * 3 + 0], vd[b * 3 + 1], vd[b * 3 + 2], &gx, &gy);

    int   off[8];
    float wt[8];
    make_offsets(gx, gy, off, wt);

    float emb[RK];
    #pragma unroll
    for (int k = 0; k < RK; ++k) {
        const float* p0 = m0 + k * HW0;
        const float* p1 = m1 + (size_t)k * HW1;
        float v = p0[off[0]] * wt[0];
        v = fmaf(p0[off[1]], wt[1], v);
        v = fmaf(p0[off[2]], wt[2], v);
        v = fmaf(p0[off[3]], wt[3], v);
        v = fmaf(p1[off[4]], wt[4], v);
        v = fmaf(p1[off[5]], wt[5], v);
        v = fmaf(p1[off[6]], wt[6], v);
        v = fmaf(p1[off[7]], wt[7], v);
        emb[k] = v;
    }

    float a0 = 0.f, a1 = 0.f, a2 = 0.f;
    #pragma unroll 8
    for (int j = 0; j < NH; ++j) {
        const float4* wp = (const float4*)&w1T[j * 16];
        float4 c0 = wp[0], c1 = wp[1], c2 = wp[2], c3 = wp[3];
        float h;
        h = emb[0] * c0.x;
        h = fmaf(emb[1],  c0.y, h);
        h = fmaf(emb[2],  c0.z, h);
        h = fmaf(emb[3],  c0.w, h);
        h = fmaf(emb[4],  c1.x, h);
        h = fmaf(emb[5],  c1.y, h);
        h = fmaf(emb[6],  c1.z, h);
        h = fmaf(emb[7],  c1.w, h);
        h = fmaf(emb[8],  c2.x, h);
        h = fmaf(emb[9],  c2.y, h);
        h = fmaf(emb[10], c2.z, h);
        h = fmaf(emb[11], c2.w, h);
        h = fmaf(emb[12], c3.x, h);
        h = fmaf(emb[13], c3.y, h);
        h = fmaf(emb[14], c3.z, h);
        h = fmaf(emb[15], c3.w, h);
        h = fmaxf(h, 0.f);
        a0 = fmaf(h, w2s[j * 4 + 0], a0);
        a1 = fmaf(h, w2s[j * 4 + 1], a1);
        a2 = fmaf(h, w2s[j * 4 + 2], a2);
    }

    out[b * 3 + 0] = softplusf(a0);
    out[b * 3 + 1] = softplusf(a1);
    out[b * 3 + 2] = softplusf(a2);
}

extern "C" void kernel_launch(void* const* d_in, const int* in_sizes, int n_in,
                              void* d_out, int out_size, void* d_ws, size_t ws_size,
                              hipStream_t stream) {
    const float* vd = (const float*)d_in[0];
    const float* m0 = (const float*)d_in[1];
    const float* m1 = (const float*)d_in[2];
    const float* w1 = (const float*)d_in[3];
    const float* w2 = (const float*)d_in[4];
    float* out = (float*)d_out;
    int B = in_sizes[0] / 3;
    int grid = (B + BLK - 1) / BLK;

    // ws layout: m1p (HW1*32 B) | m0p (HW0*32 B) | wprep (2560 floats)
    size_t m1p_b = (size_t)HW1 * 32;
    size_t m0p_b = (size_t)HW0 * 32;
    size_t wp_b  = (size_t)(NH * 16 + NH * 4) * 4;
    size_t need  = m1p_b + m0p_b + wp_b;

    if (ws_size >= need) {
        unsigned* m1p = (unsigned*)d_ws;
        unsigned* m0p = (unsigned*)((char*)d_ws + m1p_b);
        float*    wp  = (float*)((char*)d_ws + m1p_b + m0p_b);
        repack_kernel<<<(HW1 + BLK - 1) / BLK, BLK, 0, stream>>>(m1, m1p, HW1);
        repack_kernel<<<(HW0 + BLK - 1) / BLK, BLK, 0, stream>>>(m0, m0p, HW0);
        prep_weights_kernel<<<(NH * 16 + BLK - 1) / BLK, BLK, 0, stream>>>(w1, w2, wp);
        bg_gather_kernel<<<grid, BLK, 0, stream>>>(vd, m0p, m1p, wp, wp + NH * 16, out, B);
    } else {
        bg_fused_kernel<<<grid, BLK, 0, stream>>>(vd, m0, m1, w1, w2, out, B);
    }
}